// Round 11
// baseline (280.475 us; speedup 1.0000x reference)
//
#include <hip/hip_runtime.h>

#define HH 64
#define WW 64

typedef _Float16 f16;
typedef f16 f16x8 __attribute__((ext_vector_type(8)));
typedef f16 f16x4 __attribute__((ext_vector_type(4)));
typedef float f32x4 __attribute__((ext_vector_type(4)));

// ws: ws[0..63] = fp32 logit bias; then f16 region (offsets in halves):
#define M1_H 0         // [c][r*4+s][lane][j] : 49152
#define BU_H 49152     // [c][r*4+s][lane][j] : 49152
#define BF_H 98304     // [g][r][lane][j]     : 12288
#define BC_H 110592    // [c2][s][lane][j]    : 4096
#define PREP_N (64 + 114688)

// prep: R8-proven form.
__global__ __launch_bounds__(256) void prep_kernel(
    const float* __restrict__ attw, const float* __restrict__ ctw,
    const float* __restrict__ ctb, const float* __restrict__ few,
    const float* __restrict__ caw, float* __restrict__ ws) {
  int i = blockIdx.x * 256 + threadIdx.x;
  if (i >= PREP_N) return;
  f16* hb = (f16*)(ws + 64);
  if (i < 64) {
    int s = i >> 4, l15 = i & 15;
    int o = 2 * s + (l15 >> 3), n = l15 & 7;
    float acc = 0.f;
    for (int c = 0; c < 8; ++c)
      for (int d = 0; d < 8; ++d)
        acc += ctb[c * 64 + d * 8 + n] * attw[d * 512 + c * 64 + n * 8 + o];
    ws[i] = acc;
    return;
  }
  int z = i - 64;
  if (z < BU_H) {
    int j = z & 7, lane = (z >> 3) & 63, rest = z >> 9;
    int rs = rest % 12, c = rest / 12;
    int r = rs >> 2, s = rs & 3;
    int q = lane >> 4, l15 = lane & 15;
    int t = r * 4 + q;
    int o = 2 * s + (l15 >> 3), n = l15 & 7;
    float acc = 0.f;
    if (t < 9)
      for (int d = 0; d < 8; ++d)
        acc += ctw[(t * 8 + j) * 512 + c * 64 + d * 8 + n] *
               attw[d * 512 + c * 64 + n * 8 + o];
    hb[M1_H + z] = (f16)acc;
  } else if (z < BF_H) {
    int z2 = z - BU_H;
    int j = z2 & 7, lane = (z2 >> 3) & 63, rest = z2 >> 9;
    int rs = rest % 12, c = rest / 12;
    int r = rs >> 2, s = rs & 3;
    int q = lane >> 4, l15 = lane & 15;
    int t = r * 4 + q;
    int d = 2 * s + (l15 >> 3), n = l15 & 7;
    float v = (t < 9) ? ctw[(t * 8 + j) * 512 + c * 64 + d * 8 + n] : 0.f;
    hb[z] = (f16)v;
  } else if (z < BC_H) {
    int z2 = z - BF_H;
    int j = z2 & 7, lane = (z2 >> 3) & 63, rest = z2 >> 9;
    int r = rest % 3, g = rest / 3;
    int q = lane >> 4, l15 = lane & 15;
    int t = r * 4 + q;
    int d = 2 * (j & 3) + (j >> 2);
    float v = 0.f;
    if (t < 9 && ((l15 >> 3) == (g & 1)))
      v = few[(t * 8 + d) * 64 + g * 8 + (l15 & 7)];
    hb[z] = (f16)v;
  } else if (z < 114688) {
    int z2 = z - BC_H;
    int j = z2 & 7, lane = (z2 >> 3) & 63, rest = z2 >> 9;
    int s = rest & 3, c2 = rest >> 2;
    int q = lane >> 4, l15 = lane & 15;
    int nk = c2 * 4 + q;
    int nc = 2 * s + (l15 >> 3);
    float v = (nk == nc) ? caw[j * 64 + nc * 8 + (l15 & 7)] : 0.f;
    hb[z] = (f16)v;
  }
}

// R11 = R10's verified structure (register att + shfl fold, single 34.8KB LDS
// region -> 4 blocks/CU target) with register pressure brought under the
// LDS-derived 128-VGPR cap: NO manual A/B rotation buffers anywhere. Pass 1
// is an unroll-1 loop with inline bm loads; pass 2 stays fully unrolled
// (static att4 index, rule #20) but with inline bu/cb loads the compiler may
// freely sink. Occupancy (16 waves/CU) replaces prefetch depth.
__global__ __launch_bounds__(256, 2) void caps_fused(
    const float* __restrict__ in, const float* __restrict__ ws,
    const float* __restrict__ ctb, const float* __restrict__ fb,
    const float* __restrict__ cab, float* __restrict__ out) {
  __shared__ float smem[8704];  // 34816B: xt2(34704) / vtile / h1t / outbuf
  f16* xt2 = (f16*)smem;

  int bid = blockIdx.x;
  int b = bid >> 5, t5 = bid & 31;
  int ty = t5 >> 3, tx = t5 & 7;
  int tid = threadIdx.x;
  int w = __builtin_amdgcn_readfirstlane(tid >> 6);
  int lane = tid & 63;
  int q = lane >> 4, l15 = lane & 15;
  int h = l15 >> 3, n = l15 & 7;

  const f16* hb = (const f16*)(ws + 64);
  const f16x8* m1v = (const f16x8*)(hb + M1_H);
  const f16x8* buv = (const f16x8*)(hb + BU_H);
  const f16x8* bfv = (const f16x8*)(hb + BF_H);
  const f16x8* bcv = (const f16x8*)(hb + BC_H);
  const float* lb = ws;

  // ---- fill double-halo input tile: rows rp=hy2*12+hx2 (20x12), row 240=0 ----
#pragma unroll
  for (int k = 0; k < 8; ++k) {
    int i = tid + k * 256;
    if (i < 241 * 8) {
      int c = i & 7, rp = i >> 3;
      float xs[8] = {0.f, 0.f, 0.f, 0.f, 0.f, 0.f, 0.f, 0.f};
      if (rp < 240) {
        int hy2 = rp / 12, hx2 = rp - hy2 * 12;
        int iy = ty * 16 + hy2 - 2, ix = tx * 8 + hx2 - 2;
        if (iy >= 0 && iy < HH && ix >= 0 && ix < WW) {
          const float* src = in + (((b * HH + iy) * WW + ix) * 64 + c);
#pragma unroll
          for (int d = 0; d < 8; ++d) xs[d] = src[d * 8];
        }
      }
      f16x8 pk;
#pragma unroll
      for (int d = 0; d < 8; ++d) pk[d] = (f16)xs[d];
      *(f16x8*)&xt2[rp * 72 + c * 8] = pk;
    }
  }

  // ---- per-lane A-row offsets for the 3 v-tiles (pixel hp = m*16 + l15) ----
  int hpt3[3][3];
#pragma unroll
  for (int i2 = 0; i2 < 3; ++i2) {
    int hp = (3 * w + i2) * 16 + l15;
    int pv = hp < 180;
    int hy = hp / 10, hx = hp - hy * 10;
#pragma unroll
    for (int r = 0; r < 3; ++r) {
      int t = r * 4 + q;
      int off = 240 * 72;
      if (t < 9 && pv) {
        int ky = t / 3, kx = t - ky * 3;
        off = ((hy + ky) * 12 + hx + kx) * 72;
      }
      hpt3[i2][r] = off;
    }
  }

  // ---- pass 1: logits GEMM, unroll-1 loop, inline B loads ----
  f32x4 L[3][4];
#pragma unroll
  for (int s = 0; s < 4; ++s) {
    float v0 = lb[s * 16 + l15];
    L[0][s] = (f32x4){v0, v0, v0, v0};
    L[1][s] = (f32x4){v0, v0, v0, v0};
    L[2][s] = (f32x4){v0, v0, v0, v0};
  }
  __syncthreads();  // xt2 ready

#pragma unroll 1
  for (int c = 0; c < 8; ++c) {
    f16x8 bm[12];
#pragma unroll
    for (int rs = 0; rs < 12; ++rs) bm[rs] = m1v[(c * 12 + rs) * 64 + lane];
#pragma unroll
    for (int i2 = 0; i2 < 3; ++i2) {
      f16x8 a[3];
#pragma unroll
      for (int r = 0; r < 3; ++r)
        a[r] = *(const f16x8*)&xt2[hpt3[i2][r] + c * 8];
#pragma unroll
      for (int s = 0; s < 4; ++s)
#pragma unroll
        for (int r = 0; r < 3; ++r)
          L[i2][s] = __builtin_amdgcn_mfma_f32_16x16x32_f16(
              a[r], bm[r * 4 + s], L[i2][s], 0, 0, 0);
    }
  }

  // ---- softmax -> att4 registers (verified R10 fold layout) ----
  // att4[i2][r][s] = softmax weight for o = 2s + h (own h), column n
  f16x4 att4[3][4];
#pragma unroll
  for (int i2 = 0; i2 < 3; ++i2) {
#pragma unroll
    for (int r = 0; r < 4; ++r) {
      float v0 = L[i2][0][r], v1 = L[i2][1][r], v2 = L[i2][2][r], v3 = L[i2][3][r];
      float pm = fmaxf(fmaxf(v0, v1), fmaxf(v2, v3));
      float m = fmaxf(pm, __shfl_xor(pm, 8));
      float e0 = __expf(v0 - m), e1 = __expf(v1 - m);
      float e2 = __expf(v2 - m), e3 = __expf(v3 - m);
      float ps = e0 + e1 + e2 + e3;
      float inv = 1.f / (ps + __shfl_xor(ps, 8));
      f16x4 pk;
      pk[0] = (f16)(e0 * inv);
      pk[1] = (f16)(e1 * inv);
      pk[2] = (f16)(e2 * inv);
      pk[3] = (f16)(e3 * inv);
      att4[i2][r] = pk;
    }
  }
  // no barrier: att stays in registers

  // ---- pass 2: u GEMM + register fold; FULL unroll (static att4 index),
  //      inline bu/cb loads (no forced liveness — compiler may sink) ----
  f32x4 V[3][4];
#pragma unroll
  for (int i2 = 0; i2 < 3; ++i2)
#pragma unroll
    for (int s = 0; s < 4; ++s) V[i2][s] = (f32x4){0.f, 0.f, 0.f, 0.f};

#pragma unroll
  for (int c = 0; c < 8; ++c) {
    f16x8 bu[12];
#pragma unroll
    for (int rs = 0; rs < 12; ++rs) bu[rs] = buv[(c * 12 + rs) * 64 + lane];
    float cb[4];
#pragma unroll
    for (int s = 0; s < 4; ++s) cb[s] = ctb[c * 64 + s * 16 + l15];
#pragma unroll
    for (int i2 = 0; i2 < 3; ++i2) {
      f16x8 a[3];
#pragma unroll
      for (int r = 0; r < 3; ++r)
        a[r] = *(const f16x8*)&xt2[hpt3[i2][r] + c * 8];
      f32x4 U[4];
#pragma unroll
      for (int s = 0; s < 4; ++s) U[s] = (f32x4){cb[s], cb[s], cb[s], cb[s]};
#pragma unroll
      for (int s = 0; s < 4; ++s)
#pragma unroll
        for (int r = 0; r < 3; ++r)
          U[s] = __builtin_amdgcn_mfma_f32_16x16x32_f16(
              a[r], bu[r * 4 + s], U[s], 0, 0, 0);
#pragma unroll
      for (int r = 0; r < 4; ++r) {
        // att for input-channel c, column n: holder lane l15 = (c&1)*8 + n
        float o = (float)att4[i2][r][c >> 1];  // static after unroll
        float p = __shfl_xor(o, 8);
        float af = ((c & 1) == h) ? o : p;
#pragma unroll
        for (int s = 0; s < 4; ++s) V[i2][s][r] += U[s][r] * af;
      }
    }
  }

  // ---- v -> vtile (aliases xt2 region; xt2 dead), zeros for pad pixels ----
  __syncthreads();  // all xt2 reads (pass1+pass2) complete before overwrite
  f16* vtile = (f16*)smem;
#pragma unroll
  for (int i2 = 0; i2 < 3; ++i2)
#pragma unroll
    for (int r = 0; r < 4; ++r) {
      int p = (3 * w + i2) * 16 + q * 4 + r;
      int hy = p / 10, hx = p - hy * 10;
      int gy = ty * 16 + hy - 1, gx = tx * 8 + hx - 1;
      bool val = (p < 180) && gy >= 0 && gy < HH && gx >= 0 && gx < WW;
      f16x4 st;
#pragma unroll
      for (int s = 0; s < 4; ++s)
        st[s] = val ? (f16)V[i2][s][r] : (f16)0.f;  // slot=h*4+s, d=2s+h
      *(f16x4*)&vtile[p * 72 + n * 8 + h * 4] = st;
    }
  __syncthreads();  // vtile ready (rows 180..191 zero via pad-row writes)

  // ================= stage2 body (vtile in LDS) =================
  int j7 = l15 & 7;
  int hpt[2][3];
#pragma unroll
  for (int i2 = 0; i2 < 2; ++i2) {
    int pyA = (2 * w + i2) * 2 + h;
#pragma unroll
    for (int r = 0; r < 3; ++r) {
      int t = r * 4 + q;
      int hp = 180;
      if (t < 9) {
        int ky = t / 3, kx = t - ky * 3;
        hp = (pyA + ky) * 10 + j7 + kx;
      }
      hpt[i2][r] = hp * 72;
    }
  }

  // FeaExt: col (n=2s+h, j=j7); input chunk g feeds only s = g>>1
  f32x4 Lf[2][4];
#pragma unroll
  for (int s = 0; s < 4; ++s) {
    float bvv = fb[(2 * s + h) * 8 + j7];
    Lf[0][s] = (f32x4){bvv, bvv, bvv, bvv};
    Lf[1][s] = (f32x4){bvv, bvv, bvv, bvv};
  }
#pragma unroll
  for (int g = 0; g < 8; ++g) {
    int sg = g >> 1;
#pragma unroll
    for (int r = 0; r < 3; ++r) {
      f16x8 bf = bfv[(g * 3 + r) * 64 + lane];
#pragma unroll
      for (int i2 = 0; i2 < 2; ++i2) {
        f16x8 a = *(const f16x8*)&vtile[hpt[i2][r] + g * 8];
        Lf[i2][sg] =
            __builtin_amdgcn_mfma_f32_16x16x32_f16(a, bf, Lf[i2][sg], 0, 0, 0);
      }
    }
  }
#pragma unroll
  for (int i2 = 0; i2 < 2; ++i2)
#pragma unroll
    for (int s = 0; s < 4; ++s)
#pragma unroll
      for (int r = 0; r < 4; ++r) Lf[i2][s][r] = fmaxf(Lf[i2][s][r], 0.f);

  __syncthreads();  // vtile reads done; alias h1t
  f16* h1t = (f16*)smem;  // [128][72], ch2 = n*8 + j1
#pragma unroll
  for (int i2 = 0; i2 < 2; ++i2)
#pragma unroll
    for (int s = 0; s < 4; ++s)
#pragma unroll
      for (int r = 0; r < 4; ++r)
        h1t[((2 * w + i2) * 16 + q * 4 + r) * 72 + (2 * s + h) * 8 + j7] =
            (f16)Lf[i2][s][r];
  __syncthreads();

  // CapsAct: K=64 over (j1, n) block-diag
  f32x4 Hc[2][4];
#pragma unroll
  for (int s = 0; s < 4; ++s) {
    float bvv = cab[(2 * s + h) * 8 + j7];
    Hc[0][s] = (f32x4){bvv, bvv, bvv, bvv};
    Hc[1][s] = (f32x4){bvv, bvv, bvv, bvv};
  }
#pragma unroll
  for (int c2 = 0; c2 < 2; ++c2) {
    f16x8 a2[2];
#pragma unroll
    for (int i2 = 0; i2 < 2; ++i2)
      a2[i2] = *(const f16x8*)&h1t[((2 * w + i2) * 16 + l15) * 72 + c2 * 32 + q * 8];
#pragma unroll
    for (int s = 0; s < 4; ++s) {
      f16x8 bc = bcv[(c2 * 4 + s) * 64 + lane];
#pragma unroll
      for (int i2 = 0; i2 < 2; ++i2)
        Hc[i2][s] =
            __builtin_amdgcn_mfma_f32_16x16x32_f16(a2[i2], bc, Hc[i2][s], 0, 0, 0);
    }
  }

  __syncthreads();  // h1t reads done; alias outbuf
  float* outbuf = smem;  // [128][68], ch = j2*8 + n
#pragma unroll
  for (int i2 = 0; i2 < 2; ++i2)
#pragma unroll
    for (int s = 0; s < 4; ++s)
#pragma unroll
      for (int r = 0; r < 4; ++r)
        outbuf[((2 * w + i2) * 16 + q * 4 + r) * 68 + j7 * 8 + 2 * s + h] =
            Hc[i2][s][r];
  __syncthreads();

  for (int idx = tid; idx < 2048; idx += 256) {
    int p = idx >> 4, q4 = idx & 15;
    float4 val = *(float4*)&outbuf[p * 68 + q4 * 4];
    int gy = ty * 16 + (p >> 3), gx = tx * 8 + (p & 7);
    *(float4*)(out + ((b * HH + gy) * WW + gx) * 64 + q4 * 4) = val;
  }
}

extern "C" void kernel_launch(void* const* d_in, const int* in_sizes, int n_in,
                              void* d_out, int out_size, void* d_ws, size_t ws_size,
                              hipStream_t stream) {
  const float* inputs = (const float*)d_in[0];
  const float* attw   = (const float*)d_in[1];
  const float* ctw    = (const float*)d_in[2];
  const float* ctb    = (const float*)d_in[3];
  const float* few    = (const float*)d_in[4];
  const float* fb     = (const float*)d_in[5];
  const float* caw    = (const float*)d_in[6];
  const float* cab    = (const float*)d_in[7];
  float* out = (float*)d_out;
  float* ws  = (float*)d_ws;

  prep_kernel<<<(PREP_N + 255) / 256, 256, 0, stream>>>(attw, ctw, ctb, few, caw, ws);
  caps_fused<<<32 * 32, 256, 0, stream>>>(inputs, ws, ctb, fb, cab, out);
}

// Round 12
// 158.191 us; speedup vs baseline: 1.7730x; 1.7730x over previous
//
#include <hip/hip_runtime.h>

#define HH 64
#define WW 64

typedef _Float16 f16;
typedef f16 f16x8 __attribute__((ext_vector_type(8)));
typedef f16 f16x4 __attribute__((ext_vector_type(4)));
typedef float f32x4 __attribute__((ext_vector_type(4)));

typedef __attribute__((address_space(3))) void lds_void;
typedef __attribute__((address_space(1))) const void gbl_void;

// ws: ws[0..63] = fp32 logit bias; then f16 region (offsets in halves):
#define M1_H 0         // [c][r*4+s][lane][j] : 49152
#define BU_H 49152     // [c][r*4+s][lane][j] : 49152
#define BF_H 98304     // [g][r][lane][j]     : 12288
#define BC_H 110592    // [c2][s][lane][j]    : 4096
#define VT_H 114688    // [pixel][ch=n*8+slot]: 8388608  (slot: d=2*(slot&3)+(slot>>2))
#define PREP_N (64 + 114688)

__global__ __launch_bounds__(256) void prep_kernel(
    const float* __restrict__ attw, const float* __restrict__ ctw,
    const float* __restrict__ ctb, const float* __restrict__ few,
    const float* __restrict__ caw, float* __restrict__ ws) {
  int i = blockIdx.x * 256 + threadIdx.x;
  if (i >= PREP_N) return;
  f16* hb = (f16*)(ws + 64);
  if (i < 64) {
    int s = i >> 4, l15 = i & 15;
    int o = 2 * s + (l15 >> 3), n = l15 & 7;
    float acc = 0.f;
    for (int c = 0; c < 8; ++c)
      for (int d = 0; d < 8; ++d)
        acc += ctb[c * 64 + d * 8 + n] * attw[d * 512 + c * 64 + n * 8 + o];
    ws[i] = acc;
    return;
  }
  int z = i - 64;
  if (z < BU_H) {
    int j = z & 7, lane = (z >> 3) & 63, rest = z >> 9;
    int rs = rest % 12, c = rest / 12;
    int r = rs >> 2, s = rs & 3;
    int q = lane >> 4, l15 = lane & 15;
    int t = r * 4 + q;
    int o = 2 * s + (l15 >> 3), n = l15 & 7;
    float acc = 0.f;
    if (t < 9)
      for (int d = 0; d < 8; ++d)
        acc += ctw[(t * 8 + j) * 512 + c * 64 + d * 8 + n] *
               attw[d * 512 + c * 64 + n * 8 + o];
    hb[M1_H + z] = (f16)acc;
  } else if (z < BF_H) {
    int z2 = z - BU_H;
    int j = z2 & 7, lane = (z2 >> 3) & 63, rest = z2 >> 9;
    int rs = rest % 12, c = rest / 12;
    int r = rs >> 2, s = rs & 3;
    int q = lane >> 4, l15 = lane & 15;
    int t = r * 4 + q;
    int d = 2 * s + (l15 >> 3), n = l15 & 7;
    float v = (t < 9) ? ctw[(t * 8 + j) * 512 + c * 64 + d * 8 + n] : 0.f;
    hb[z] = (f16)v;
  } else if (z < BC_H) {
    int z2 = z - BF_H;
    int j = z2 & 7, lane = (z2 >> 3) & 63, rest = z2 >> 9;
    int r = rest % 3, g = rest / 3;
    int q = lane >> 4, l15 = lane & 15;
    int t = r * 4 + q;
    int d = 2 * (j & 3) + (j >> 2);
    float v = 0.f;
    if (t < 9 && ((l15 >> 3) == (g & 1)))
      v = few[(t * 8 + d) * 64 + g * 8 + (l15 & 7)];
    hb[z] = (f16)v;
  } else if (z < VT_H) {
    int z2 = z - BC_H;
    int j = z2 & 7, lane = (z2 >> 3) & 63, rest = z2 >> 9;
    int s = rest & 3, c2 = rest >> 2;
    int q = lane >> 4, l15 = lane & 15;
    int nk = c2 * 4 + q;
    int nc = 2 * s + (l15 >> 3);
    float v = (nk == nc) ? caw[j * 64 + nc * 8 + (l15 & 7)] : 0.f;
    hb[z] = (f16)v;
  }
}

// Stage 1: R5-proven skeleton (LDS-staged B via global_load_lds, dbuf,
// one __syncthreads per c-step) with the attb LDS buffer ELIMINATED:
// softmax output stays in f16x4 registers; pass-2 fold = one __shfl_xor(.,8)
// (layout verified in R10/R11). LDS 69120 -> 50640 B => LDS-derived target
// 3 blocks/CU with VGPR cap 170 > ~120 demand (first occupancy push where
// cap exceeds demand). Pass-2 c-loop fully unrolled (static att4 index).
// Epilogue vtmp aliases xt (dead after pass 2).
__global__ __launch_bounds__(256, 2) void caps_stage1(
    const float* __restrict__ in, const float* __restrict__ ws,
    const float* __restrict__ ctb, f16* __restrict__ vt) {
  __shared__ f16 xt[181 * 72];     // 26064 B, hp=180 = zero row; reused as vtmp
  __shared__ f16 bstage[2][6144];  // 2 x 12 KB B-fragment slices
  int bid = blockIdx.x;
  int b = bid >> 5, t5 = bid & 31;
  int ty = t5 >> 3, tx = t5 & 7;
  int tid = threadIdx.x;
  int w = __builtin_amdgcn_readfirstlane(tid >> 6);
  int lane = tid & 63;
  int q = lane >> 4, l15 = lane & 15;
  int h = l15 >> 3, n = l15 & 7;

  const f16* hb = (const f16*)(ws + 64);
  const f16* m1h = hb + M1_H;
  const f16* buh = hb + BU_H;
  const float* lb = ws;

  // cooperative stage of one 12KB c-slice: wave w handles rows 3w..3w+2.
  auto stage = [&](const f16* src, int c, int bufi) {
    const f16* gs = src + c * 6144 + (w * 3) * 512 + lane * 8;
#pragma unroll
    for (int j = 0; j < 3; ++j)
      __builtin_amdgcn_global_load_lds(
          (gbl_void*)(gs + j * 512),
          (lds_void*)&bstage[bufi][(w * 3 + j) * 512], 16, 0, 0);
  };

  // prologue: stage M1 c=0,1 under the halo fill
  stage(m1h, 0, 0);
  stage(m1h, 1, 1);

  // fill halo tile (fp32 -> f16, transpose to ch = c*8+dd)
#pragma unroll
  for (int k = 0; k < 6; ++k) {
    int i = tid + k * 256;
    if (i < 181 * 8) {
      int c = i & 7, hp = i >> 3;
      float xs[8] = {0.f, 0.f, 0.f, 0.f, 0.f, 0.f, 0.f, 0.f};
      if (hp < 180) {
        int hy = hp / 10, hx = hp - hy * 10;
        int gy = ty * 16 + hy - 1, gx = tx * 8 + hx - 1;
        if (gy >= 0 && gy < HH && gx >= 0 && gx < WW) {
          const float* src = in + (((b * HH + gy) * WW + gx) * 64 + c);
#pragma unroll
          for (int d = 0; d < 8; ++d) xs[d] = src[d * 8];
        }
      }
      f16x8 pk;
#pragma unroll
      for (int d = 0; d < 8; ++d) pk[d] = (f16)xs[d];
      *(f16x8*)&xt[hp * 72 + c * 8] = pk;
    }
  }

  int hpt[2][3];
#pragma unroll
  for (int i2 = 0; i2 < 2; ++i2) {
    int pyA = (2 * w + i2) * 2 + h;
    int pxA = l15 & 7;
#pragma unroll
    for (int r = 0; r < 3; ++r) {
      int t = r * 4 + q;
      int hp = 180;
      if (t < 9) {
        int ky = t / 3, kx = t - ky * 3;
        hp = (pyA + ky) * 10 + pxA + kx;
      }
      hpt[i2][r] = hp * 72;
    }
  }

  f32x4 L[2][4];
#pragma unroll
  for (int s = 0; s < 4; ++s) {
    float v0 = lb[s * 16 + l15];
    L[0][s] = (f32x4){v0, v0, v0, v0};
    L[1][s] = (f32x4){v0, v0, v0, v0};
  }
  __syncthreads();  // halo ready + bstage c=0,1 landed (vmcnt drained)

  auto ldsB = [&](int bufi, f16x8(&bm)[12]) {
#pragma unroll
    for (int rs = 0; rs < 12; ++rs)
      bm[rs] = *(const f16x8*)&bstage[bufi][rs * 512 + lane * 8];
  };

  // ---- pass 1: logits GEMM, LDS-staged B (R5 verbatim) ----
  auto p1step = [&](int c, int bufi) {
    f16x8 bm[12];
    ldsB(bufi, bm);
    f16x8 a[2][3];
#pragma unroll
    for (int i2 = 0; i2 < 2; ++i2)
#pragma unroll
      for (int r = 0; r < 3; ++r)
        a[i2][r] = *(const f16x8*)&xt[hpt[i2][r] + c * 8];
#pragma unroll
    for (int i2 = 0; i2 < 2; ++i2)
#pragma unroll
      for (int s = 0; s < 4; ++s)
#pragma unroll
        for (int r = 0; r < 3; ++r)
          L[i2][s] = __builtin_amdgcn_mfma_f32_16x16x32_f16(
              a[i2][r], bm[r * 4 + s], L[i2][s], 0, 0, 0);
  };

#pragma unroll 1
  for (int cc = 0; cc < 4; ++cc) {
    int c0 = 2 * cc;
    p1step(c0, 0);
    __syncthreads();  // all waves done with buf0; staged buf1 landed
    if (cc < 3) stage(m1h, c0 + 2, 0); else stage(buh, 0, 0);
    p1step(c0 + 1, 1);
    __syncthreads();  // all waves done with buf1; staged buf0 landed
    if (cc < 3) stage(m1h, c0 + 3, 1); else stage(buh, 1, 1);
  }

  // pass2 bias c=0,1: latency hides under softmax
  float cbA[4], cbB[4];
#pragma unroll
  for (int s = 0; s < 4; ++s) {
    cbA[s] = ctb[s * 16 + l15];
    cbB[s] = ctb[64 + s * 16 + l15];
  }

  // ---- softmax -> att4 registers (R10/R11-verified fold layout) ----
  // att4[i2][r][s] = softmax weight for o = 2s + h (own h), column n
  f16x4 att4[2][4];
#pragma unroll
  for (int i2 = 0; i2 < 2; ++i2) {
#pragma unroll
    for (int r = 0; r < 4; ++r) {
      float v0 = L[i2][0][r], v1 = L[i2][1][r], v2 = L[i2][2][r], v3 = L[i2][3][r];
      float pm = fmaxf(fmaxf(v0, v1), fmaxf(v2, v3));
      float m = fmaxf(pm, __shfl_xor(pm, 8));
      float e0 = __expf(v0 - m), e1 = __expf(v1 - m);
      float e2 = __expf(v2 - m), e3 = __expf(v3 - m);
      float ps = e0 + e1 + e2 + e3;
      float inv = 1.f / (ps + __shfl_xor(ps, 8));
      f16x4 pk;
      pk[0] = (f16)(e0 * inv);
      pk[1] = (f16)(e1 * inv);
      pk[2] = (f16)(e2 * inv);
      pk[3] = (f16)(e3 * inv);
      att4[i2][r] = pk;
    }
  }
  __syncthreads();  // BU c=0,1 staging landed (stage issued at cc==3 above)

  // ---- pass 2: u GEMM + register fold; FULL unroll (static att4 index),
  //      R5's dbuf staging/barrier skeleton preserved ----
  f32x4 V[2][4];
#pragma unroll
  for (int s = 0; s < 4; ++s) {
    V[0][s] = (f32x4){0.f, 0.f, 0.f, 0.f};
    V[1][s] = (f32x4){0.f, 0.f, 0.f, 0.f};
  }

  auto p2step = [&](int c, int bufi, const float(&cb)[4]) {
    f16x8 bm[12];
    ldsB(bufi, bm);
#pragma unroll
    for (int i2 = 0; i2 < 2; ++i2) {
      f16x8 a[3];
#pragma unroll
      for (int r = 0; r < 3; ++r)
        a[r] = *(const f16x8*)&xt[hpt[i2][r] + c * 8];
      f32x4 U[4];
#pragma unroll
      for (int s = 0; s < 4; ++s) U[s] = (f32x4){cb[s], cb[s], cb[s], cb[s]};
#pragma unroll
      for (int s = 0; s < 4; ++s)
#pragma unroll
        for (int r = 0; r < 3; ++r)
          U[s] = __builtin_amdgcn_mfma_f32_16x16x32_f16(
              a[r], bm[r * 4 + s], U[s], 0, 0, 0);
#pragma unroll
      for (int r = 0; r < 4; ++r) {
        // att for input-channel c, column n: holder lane l15 = (c&1)*8 + n
        float o = (float)att4[i2][r][c >> 1];  // static after full unroll
        float p = __shfl_xor(o, 8);
        float af = ((c & 1) == h) ? o : p;
#pragma unroll
        for (int s = 0; s < 4; ++s) V[i2][s][r] += U[s][r] * af;
      }
    }
  };

#pragma unroll
  for (int cc = 0; cc < 4; ++cc) {
    int c0 = 2 * cc;
    p2step(c0, 0, cbA);
    __syncthreads();
    if (cc < 3) {
      stage(buh, c0 + 2, 0);
#pragma unroll
      for (int s = 0; s < 4; ++s) cbA[s] = ctb[(c0 + 2) * 64 + s * 16 + l15];
    }
    p2step(c0 + 1, 1, cbB);
    __syncthreads();
    if (cc < 3) {
      stage(buh, c0 + 3, 1);
#pragma unroll
      for (int s = 0; s < 4; ++s) cbB[s] = ctb[(c0 + 3) * 64 + s * 16 + l15];
    }
  }
  // loop ended with __syncthreads: all xt reads complete -> safe to alias

  // ---- epilogue: transpose V through vtmp (aliases xt), coalesced stores ----
  f16* vtmp = xt;
#pragma unroll
  for (int i2 = 0; i2 < 2; ++i2)
#pragma unroll
    for (int r = 0; r < 4; ++r) {
      int p = (2 * w + i2) * 16 + q * 4 + r;
      f16x4 st;
#pragma unroll
      for (int s = 0; s < 4; ++s) st[s] = (f16)V[i2][s][r];  // slot=h*4+s, d=2s+h
      *(f16x4*)&vtmp[p * 72 + n * 8 + h * 4] = st;
    }
  __syncthreads();
  for (int idx = tid; idx < 1024; idx += 256) {
    int p = idx >> 3, q2 = idx & 7;
    float4 val = *(float4*)&vtmp[p * 72 + q2 * 8];
    int gy = ty * 16 + (p >> 3), gx = tx * 8 + (p & 7);
    ((float4*)(vt + ((b * HH + gy) * WW + gx) * 64))[q2] = val;
  }
}

// Stage 2: R5-proven form verbatim (R1 structure + bcf preload under fill).
__global__ __launch_bounds__(256, 2) void caps_stage2(
    const f16* __restrict__ vt, const float* __restrict__ ws,
    const float* __restrict__ fb, const float* __restrict__ cab,
    float* __restrict__ out) {
  __shared__ float smemf[8704];  // 34.8 KB: vtile / h1t / outbuf aliased
  f16* vtile = (f16*)smemf;
  int bid = blockIdx.x;
  int b = bid >> 5, t5 = bid & 31;
  int ty = t5 >> 3, tx = t5 & 7;
  int tid = threadIdx.x;
  int w = __builtin_amdgcn_readfirstlane(tid >> 6);
  int lane = tid & 63;

  const f16x8* bfv = (const f16x8*)((const f16*)(ws + 64) + BF_H);
  const f16x8* bcv = (const f16x8*)((const f16*)(ws + 64) + BC_H);

  // preload CapsAct B-frags: latency hides under fill + FeaExt
  f16x8 bcf[8];
#pragma unroll
  for (int k = 0; k < 8; ++k) bcf[k] = bcv[k * 64 + lane];

  for (int i = tid; i < 181 * 8; i += 256) {
    int q2 = i & 7, hp = i >> 3;
    float4 val = make_float4(0.f, 0.f, 0.f, 0.f);
    if (hp < 180) {
      int hy = hp / 10, hx = hp - hy * 10;
      int gy = ty * 16 + hy - 1, gx = tx * 8 + hx - 1;
      if (gy >= 0 && gy < HH && gx >= 0 && gx < WW)
        val = ((const float4*)(vt + ((b * HH + gy) * WW + gx) * 64))[q2];
    }
    *(float4*)&vtile[hp * 72 + q2 * 8] = val;
  }
  __syncthreads();

  int q = lane >> 4, l15 = lane & 15;
  int h = l15 >> 3, j7 = l15 & 7;

  int hpt[2][3];
#pragma unroll
  for (int i2 = 0; i2 < 2; ++i2) {
    int pyA = (2 * w + i2) * 2 + h;
#pragma unroll
    for (int r = 0; r < 3; ++r) {
      int t = r * 4 + q;
      int hp = 180;
      if (t < 9) {
        int ky = t / 3, kx = t - ky * 3;
        hp = (pyA + ky) * 10 + j7 + kx;
      }
      hpt[i2][r] = hp * 72;
    }
  }

  // FeaExt: col (n=2s+h, j=j7); input chunk g feeds only s = g>>1
  f32x4 L[2][4];
#pragma unroll
  for (int s = 0; s < 4; ++s) {
    float bvv = fb[(2 * s + h) * 8 + j7];
    L[0][s] = (f32x4){bvv, bvv, bvv, bvv};
    L[1][s] = (f32x4){bvv, bvv, bvv, bvv};
  }
#pragma unroll
  for (int g = 0; g < 8; ++g) {
    int sg = g >> 1;
#pragma unroll
    for (int r = 0; r < 3; ++r) {
      f16x8 bf = bfv[(g * 3 + r) * 64 + lane];
#pragma unroll
      for (int i2 = 0; i2 < 2; ++i2) {
        f16x8 a = *(const f16x8*)&vtile[hpt[i2][r] + g * 8];
        L[i2][sg] = __builtin_amdgcn_mfma_f32_16x16x32_f16(a, bf, L[i2][sg], 0, 0, 0);
      }
    }
  }
#pragma unroll
  for (int i2 = 0; i2 < 2; ++i2)
#pragma unroll
    for (int s = 0; s < 4; ++s)
#pragma unroll
      for (int r = 0; r < 4; ++r) L[i2][s][r] = fmaxf(L[i2][s][r], 0.f);

  __syncthreads();  // vtile reads done; alias h1t
  f16* h1t = (f16*)smemf;  // [128][72], ch2 = n*8 + j1
#pragma unroll
  for (int i2 = 0; i2 < 2; ++i2)
#pragma unroll
    for (int s = 0; s < 4; ++s)
#pragma unroll
      for (int r = 0; r < 4; ++r)
        h1t[((2 * w + i2) * 16 + q * 4 + r) * 72 + (2 * s + h) * 8 + j7] =
            (f16)L[i2][s][r];
  __syncthreads();

  // CapsAct: K=64 over (j1, n) block-diag
  f32x4 H[2][4];
#pragma unroll
  for (int s = 0; s < 4; ++s) {
    float bvv = cab[(2 * s + h) * 8 + j7];
    H[0][s] = (f32x4){bvv, bvv, bvv, bvv};
    H[1][s] = (f32x4){bvv, bvv, bvv, bvv};
  }
#pragma unroll
  for (int c2 = 0; c2 < 2; ++c2) {
    f16x8 a2[2];
#pragma unroll
    for (int i2 = 0; i2 < 2; ++i2)
      a2[i2] = *(const f16x8*)&h1t[((2 * w + i2) * 16 + l15) * 72 + c2 * 32 + q * 8];
#pragma unroll
    for (int s = 0; s < 4; ++s) {
#pragma unroll
      for (int i2 = 0; i2 < 2; ++i2)
        H[i2][s] = __builtin_amdgcn_mfma_f32_16x16x32_f16(
            a2[i2], bcf[c2 * 4 + s], H[i2][s], 0, 0, 0);
    }
  }

  __syncthreads();  // h1t reads done; alias outbuf
  float* outbuf = smemf;  // [128][68], ch = j2*8 + n
#pragma unroll
  for (int i2 = 0; i2 < 2; ++i2)
#pragma unroll
    for (int s = 0; s < 4; ++s)
#pragma unroll
      for (int r = 0; r < 4; ++r)
        outbuf[((2 * w + i2) * 16 + q * 4 + r) * 68 + j7 * 8 + 2 * s + h] =
            H[i2][s][r];
  __syncthreads();

  for (int idx = tid; idx < 2048; idx += 256) {
    int p = idx >> 4, q4 = idx & 15;
    float4 val = *(float4*)&outbuf[p * 68 + q4 * 4];
    int gy = ty * 16 + (p >> 3), gx = tx * 8 + (p & 7);
    *(float4*)(out + ((b * HH + gy) * WW + gx) * 64 + q4 * 4) = val;
  }
}

extern "C" void kernel_launch(void* const* d_in, const int* in_sizes, int n_in,
                              void* d_out, int out_size, void* d_ws, size_t ws_size,
                              hipStream_t stream) {
  const float* inputs = (const float*)d_in[0];
  const float* attw   = (const float*)d_in[1];
  const float* ctw    = (const float*)d_in[2];
  const float* ctb    = (const float*)d_in[3];
  const float* few    = (const float*)d_in[4];
  const float* fb     = (const float*)d_in[5];
  const float* caw    = (const float*)d_in[6];
  const float* cab    = (const float*)d_in[7];
  float* out = (float*)d_out;
  float* ws  = (float*)d_ws;
  f16* vt = (f16*)(ws + 64) + VT_H;

  prep_kernel<<<(PREP_N + 255) / 256, 256, 0, stream>>>(attw, ctw, ctb, few, caw, ws);
  caps_stage1<<<32 * 32, 256, 0, stream>>>(inputs, ws, ctb, vt);
  caps_stage2<<<32 * 32, 256, 0, stream>>>(vt, ws, fb, cab, out);
}

// Round 13
// 148.053 us; speedup vs baseline: 1.8944x; 1.0685x over previous
//
#include <hip/hip_runtime.h>

#define HH 64
#define WW 64

typedef _Float16 f16;
typedef f16 f16x8 __attribute__((ext_vector_type(8)));
typedef f16 f16x4 __attribute__((ext_vector_type(4)));
typedef float f32x4 __attribute__((ext_vector_type(4)));

typedef __attribute__((address_space(3))) void lds_void;
typedef __attribute__((address_space(1))) const void gbl_void;

// ws: ws[0..63] = fp32 logit bias; then f16 region (offsets in halves):
#define M1_H 0         // [c][r*4+s][lane][j] : 49152
#define BU_H 49152     // [c][r*4+s][lane][j] : 49152
#define BF_H 98304     // [g][r][lane][j]     : 12288
#define BC_H 110592    // [c2][s][lane][j]    : 4096
#define VT_H 114688    // [pixel][ch=n*8+slot]: 8388608  (slot: d=2*(slot&3)+(slot>>2))
#define PREP_N (64 + 114688)

__global__ __launch_bounds__(256) void prep_kernel(
    const float* __restrict__ attw, const float* __restrict__ ctw,
    const float* __restrict__ ctb, const float* __restrict__ few,
    const float* __restrict__ caw, float* __restrict__ ws) {
  int i = blockIdx.x * 256 + threadIdx.x;
  if (i >= PREP_N) return;
  f16* hb = (f16*)(ws + 64);
  if (i < 64) {
    int s = i >> 4, l15 = i & 15;
    int o = 2 * s + (l15 >> 3), n = l15 & 7;
    float acc = 0.f;
    for (int c = 0; c < 8; ++c)
      for (int d = 0; d < 8; ++d)
        acc += ctb[c * 64 + d * 8 + n] * attw[d * 512 + c * 64 + n * 8 + o];
    ws[i] = acc;
    return;
  }
  int z = i - 64;
  if (z < BU_H) {
    int j = z & 7, lane = (z >> 3) & 63, rest = z >> 9;
    int rs = rest % 12, c = rest / 12;
    int r = rs >> 2, s = rs & 3;
    int q = lane >> 4, l15 = lane & 15;
    int t = r * 4 + q;
    int o = 2 * s + (l15 >> 3), n = l15 & 7;
    float acc = 0.f;
    if (t < 9)
      for (int d = 0; d < 8; ++d)
        acc += ctw[(t * 8 + j) * 512 + c * 64 + d * 8 + n] *
               attw[d * 512 + c * 64 + n * 8 + o];
    hb[M1_H + z] = (f16)acc;
  } else if (z < BF_H) {
    int z2 = z - BU_H;
    int j = z2 & 7, lane = (z2 >> 3) & 63, rest = z2 >> 9;
    int rs = rest % 12, c = rest / 12;
    int r = rs >> 2, s = rs & 3;
    int q = lane >> 4, l15 = lane & 15;
    int t = r * 4 + q;
    int d = 2 * s + (l15 >> 3), n = l15 & 7;
    float v = (t < 9) ? ctw[(t * 8 + j) * 512 + c * 64 + d * 8 + n] : 0.f;
    hb[z] = (f16)v;
  } else if (z < BC_H) {
    int z2 = z - BF_H;
    int j = z2 & 7, lane = (z2 >> 3) & 63, rest = z2 >> 9;
    int r = rest % 3, g = rest / 3;
    int q = lane >> 4, l15 = lane & 15;
    int t = r * 4 + q;
    int d = 2 * (j & 3) + (j >> 2);
    float v = 0.f;
    if (t < 9 && ((l15 >> 3) == (g & 1)))
      v = few[(t * 8 + d) * 64 + g * 8 + (l15 & 7)];
    hb[z] = (f16)v;
  } else if (z < VT_H) {
    int z2 = z - BC_H;
    int j = z2 & 7, lane = (z2 >> 3) & 63, rest = z2 >> 9;
    int s = rest & 3, c2 = rest >> 2;
    int q = lane >> 4, l15 = lane & 15;
    int nk = c2 * 4 + q;
    int nc = 2 * s + (l15 >> 3);
    float v = (nk == nc) ? caw[j * 64 + nc * 8 + (l15 & 7)] : 0.f;
    hb[z] = (f16)v;
  }
}

// Stage 1 (R13): R5's proven structure (LDS-staged B, dbuf, LDS attb fold)
// with staging re-grained from 12KB c-slices to 4KB r-slices. LDS total
// 69120 -> 52688 B (xt 26064 + attb 18432 + bstage 8192) => 3 blocks/CU.
// Register demand stays R5-class (~115 < 128-cap) => no spill possible in
// the 3-block residency class (R12's failure mode eliminated). Distance-2
// slice rotation; per-slice: 1 global_load_lds per wave; one barrier per
// slice (its vmcnt drain = pipeline wait). Pass-2 bias folded at the end
// as (U + cb)*att so U inits to zero and cb latency hides under r-steps.
__global__ __launch_bounds__(256, 2) void caps_stage1(
    const float* __restrict__ in, const float* __restrict__ ws,
    const float* __restrict__ ctb, f16* __restrict__ vt) {
  __shared__ f16 xt[181 * 72];     // 26064 B, hp=180 = zero row
  __shared__ f16 attb[128 * 72];   // 18432 B; reused as vtmp in epilogue
  __shared__ f16 bstage[2][2048];  // 2 x 4 KB r-slices (4 rs-rows each)
  int bid = blockIdx.x;
  int b = bid >> 5, t5 = bid & 31;
  int ty = t5 >> 3, tx = t5 & 7;
  int tid = threadIdx.x;
  int w = __builtin_amdgcn_readfirstlane(tid >> 6);
  int lane = tid & 63;
  int q = lane >> 4, l15 = lane & 15;
  int h = l15 >> 3, n = l15 & 7;

  const f16* hb = (const f16*)(ws + 64);
  const f16* m1h = hb + M1_H;
  const f16* buh = hb + BU_H;
  const float* lb = ws;

  // stage one 4KB r-slice k (= c*3+r, rows rs = 4k..4k+3): wave w -> row 4k+w.
  auto stage = [&](const f16* src, int k, int bufi) {
    __builtin_amdgcn_global_load_lds(
        (gbl_void*)(src + (4 * k + w) * 512 + lane * 8),
        (lds_void*)&bstage[bufi][w * 512], 16, 0, 0);
  };

  // prologue: stage M1 slices 0,1 under the halo fill
  stage(m1h, 0, 0);
  stage(m1h, 1, 1);

  // fill halo tile (fp32 -> f16, transpose to ch = c*8+dd)
#pragma unroll
  for (int k = 0; k < 6; ++k) {
    int i = tid + k * 256;
    if (i < 181 * 8) {
      int c = i & 7, hp = i >> 3;
      float xs[8] = {0.f, 0.f, 0.f, 0.f, 0.f, 0.f, 0.f, 0.f};
      if (hp < 180) {
        int hy = hp / 10, hx = hp - hy * 10;
        int gy = ty * 16 + hy - 1, gx = tx * 8 + hx - 1;
        if (gy >= 0 && gy < HH && gx >= 0 && gx < WW) {
          const float* src = in + (((b * HH + gy) * WW + gx) * 64 + c);
#pragma unroll
          for (int d = 0; d < 8; ++d) xs[d] = src[d * 8];
        }
      }
      f16x8 pk;
#pragma unroll
      for (int d = 0; d < 8; ++d) pk[d] = (f16)xs[d];
      *(f16x8*)&xt[hp * 72 + c * 8] = pk;
    }
  }

  int hpt[2][3];
#pragma unroll
  for (int i2 = 0; i2 < 2; ++i2) {
    int pyA = (2 * w + i2) * 2 + h;
    int pxA = l15 & 7;
#pragma unroll
    for (int r = 0; r < 3; ++r) {
      int t = r * 4 + q;
      int hp = 180;
      if (t < 9) {
        int ky = t / 3, kx = t - ky * 3;
        hp = (pyA + ky) * 10 + pxA + kx;
      }
      hpt[i2][r] = hp * 72;
    }
  }

  f32x4 L[2][4];
#pragma unroll
  for (int s = 0; s < 4; ++s) {
    float v0 = lb[s * 16 + l15];
    L[0][s] = (f32x4){v0, v0, v0, v0};
    L[1][s] = (f32x4){v0, v0, v0, v0};
  }
  __syncthreads();  // halo ready + slices 0,1 landed (vmcnt drained)

  // ---- pass 1: logits GEMM, r-sliced dbuf staging ----
#pragma unroll 1
  for (int cc = 0; cc < 8; ++cc) {
#pragma unroll
    for (int r = 0; r < 3; ++r) {
      int k = cc * 3 + r;
      int bufi = k & 1;
      f16x8 bm[4];
#pragma unroll
      for (int s = 0; s < 4; ++s)
        bm[s] = *(const f16x8*)&bstage[bufi][s * 512 + lane * 8];
      f16x8 a0 = *(const f16x8*)&xt[hpt[0][r] + cc * 8];
      f16x8 a1 = *(const f16x8*)&xt[hpt[1][r] + cc * 8];
#pragma unroll
      for (int s = 0; s < 4; ++s) {
        L[0][s] = __builtin_amdgcn_mfma_f32_16x16x32_f16(a0, bm[s], L[0][s], 0, 0, 0);
        L[1][s] = __builtin_amdgcn_mfma_f32_16x16x32_f16(a1, bm[s], L[1][s], 0, 0, 0);
      }
      __syncthreads();  // all waves done with bufi; staged slice k+1 landed
      int k2 = k + 2;
      if (k2 < 24) stage(m1h, k2, bufi);
      else stage(buh, k2 - 24, bufi);  // k=22,23 -> BU slices 0,1
    }
  }

  // ---- softmax over o (4 in-lane s-frags + lane^8), att -> LDS attb ----
#pragma unroll
  for (int i2 = 0; i2 < 2; ++i2) {
    int pbase = (2 * w + i2) * 16 + q * 4;
#pragma unroll
    for (int r = 0; r < 4; ++r) {
      float v0 = L[i2][0][r], v1 = L[i2][1][r], v2 = L[i2][2][r], v3 = L[i2][3][r];
      float pm = fmaxf(fmaxf(v0, v1), fmaxf(v2, v3));
      float m = fmaxf(pm, __shfl_xor(pm, 8));
      float e0 = __expf(v0 - m), e1 = __expf(v1 - m);
      float e2 = __expf(v2 - m), e3 = __expf(v3 - m);
      float ps = e0 + e1 + e2 + e3;
      float inv = 1.f / (ps + __shfl_xor(ps, 8));
      int ab = (pbase + r) * 72 + n * 8 + h;  // o = 2s + h
      attb[ab + 0] = (f16)(e0 * inv);
      attb[ab + 2] = (f16)(e1 * inv);
      attb[ab + 4] = (f16)(e2 * inv);
      attb[ab + 6] = (f16)(e3 * inv);
    }
  }
  __syncthreads();  // attb ready + BU slices 0,1 staging landed

  int ab[2][4];
#pragma unroll
  for (int i2 = 0; i2 < 2; ++i2)
#pragma unroll
    for (int r = 0; r < 4; ++r)
      ab[i2][r] = ((2 * w + i2) * 16 + q * 4 + r) * 72 + n * 8;

  // ---- pass 2: u GEMM + attention fold, r-sliced dbuf staging ----
  f32x4 V[2][4];
#pragma unroll
  for (int s = 0; s < 4; ++s) {
    V[0][s] = (f32x4){0.f, 0.f, 0.f, 0.f};
    V[1][s] = (f32x4){0.f, 0.f, 0.f, 0.f};
  }

#pragma unroll 1
  for (int cc = 0; cc < 8; ++cc) {
    float cb[4];  // bias, folded at the end as (U+cb)*att -> latency hides
#pragma unroll
    for (int s = 0; s < 4; ++s) cb[s] = ctb[cc * 64 + s * 16 + l15];
    f32x4 U[2][4];
#pragma unroll
    for (int i2 = 0; i2 < 2; ++i2)
#pragma unroll
      for (int s = 0; s < 4; ++s) U[i2][s] = (f32x4){0.f, 0.f, 0.f, 0.f};
#pragma unroll
    for (int r = 0; r < 3; ++r) {
      int k = cc * 3 + r;
      int bufi = k & 1;
      f16x8 bm[4];
#pragma unroll
      for (int s = 0; s < 4; ++s)
        bm[s] = *(const f16x8*)&bstage[bufi][s * 512 + lane * 8];
      f16x8 a0 = *(const f16x8*)&xt[hpt[0][r] + cc * 8];
      f16x8 a1 = *(const f16x8*)&xt[hpt[1][r] + cc * 8];
#pragma unroll
      for (int s = 0; s < 4; ++s) {
        U[0][s] = __builtin_amdgcn_mfma_f32_16x16x32_f16(a0, bm[s], U[0][s], 0, 0, 0);
        U[1][s] = __builtin_amdgcn_mfma_f32_16x16x32_f16(a1, bm[s], U[1][s], 0, 0, 0);
      }
      __syncthreads();
      int k2 = k + 2;
      if (k2 < 24) stage(buh, k2, bufi);
    }
    // fold (att via own-wave LDS rows; u = gemm + bias)
#pragma unroll
    for (int i2 = 0; i2 < 2; ++i2)
#pragma unroll
      for (int r4 = 0; r4 < 4; ++r4) {
        float af = (float)attb[ab[i2][r4] + cc];
#pragma unroll
        for (int s = 0; s < 4; ++s)
          V[i2][s][r4] += (U[i2][s][r4] + cb[s]) * af;
      }
  }
  // loop ended with __syncthreads at (cc=7,r=2); final folds read own-wave
  // attb rows only; vtmp writes below are own-wave rows after those reads.

  // ---- epilogue: transpose V through attb (as vtmp), coalesced stores ----
  f16* vtmp = attb;
#pragma unroll
  for (int i2 = 0; i2 < 2; ++i2)
#pragma unroll
    for (int r = 0; r < 4; ++r) {
      int p = (2 * w + i2) * 16 + q * 4 + r;
      f16x4 st;
#pragma unroll
      for (int s = 0; s < 4; ++s) st[s] = (f16)V[i2][s][r];  // slot=h*4+s, d=2s+h
      *(f16x4*)&vtmp[p * 72 + n * 8 + h * 4] = st;
    }
  __syncthreads();
  for (int idx = tid; idx < 1024; idx += 256) {
    int p = idx >> 3, q2 = idx & 7;
    float4 val = *(float4*)&vtmp[p * 72 + q2 * 8];
    int gy = ty * 16 + (p >> 3), gx = tx * 8 + (p & 7);
    ((float4*)(vt + ((b * HH + gy) * WW + gx) * 64))[q2] = val;
  }
}

// Stage 2: R5-proven form verbatim (R1 structure + bcf preload under fill).
__global__ __launch_bounds__(256, 2) void caps_stage2(
    const f16* __restrict__ vt, const float* __restrict__ ws,
    const float* __restrict__ fb, const float* __restrict__ cab,
    float* __restrict__ out) {
  __shared__ float smemf[8704];  // 34.8 KB: vtile / h1t / outbuf aliased
  f16* vtile = (f16*)smemf;
  int bid = blockIdx.x;
  int b = bid >> 5, t5 = bid & 31;
  int ty = t5 >> 3, tx = t5 & 7;
  int tid = threadIdx.x;
  int w = __builtin_amdgcn_readfirstlane(tid >> 6);
  int lane = tid & 63;

  const f16x8* bfv = (const f16x8*)((const f16*)(ws + 64) + BF_H);
  const f16x8* bcv = (const f16x8*)((const f16*)(ws + 64) + BC_H);

  // preload CapsAct B-frags: latency hides under fill + FeaExt
  f16x8 bcf[8];
#pragma unroll
  for (int k = 0; k < 8; ++k) bcf[k] = bcv[k * 64 + lane];

  for (int i = tid; i < 181 * 8; i += 256) {
    int q2 = i & 7, hp = i >> 3;
    float4 val = make_float4(0.f, 0.f, 0.f, 0.f);
    if (hp < 180) {
      int hy = hp / 10, hx = hp - hy * 10;
      int gy = ty * 16 + hy - 1, gx = tx * 8 + hx - 1;
      if (gy >= 0 && gy < HH && gx >= 0 && gx < WW)
        val = ((const float4*)(vt + ((b * HH + gy) * WW + gx) * 64))[q2];
    }
    *(float4*)&vtile[hp * 72 + q2 * 8] = val;
  }
  __syncthreads();

  int q = lane >> 4, l15 = lane & 15;
  int h = l15 >> 3, j7 = l15 & 7;

  int hpt[2][3];
#pragma unroll
  for (int i2 = 0; i2 < 2; ++i2) {
    int pyA = (2 * w + i2) * 2 + h;
#pragma unroll
    for (int r = 0; r < 3; ++r) {
      int t = r * 4 + q;
      int hp = 180;
      if (t < 9) {
        int ky = t / 3, kx = t - ky * 3;
        hp = (pyA + ky) * 10 + j7 + kx;
      }
      hpt[i2][r] = hp * 72;
    }
  }

  // FeaExt: col (n=2s+h, j=j7); input chunk g feeds only s = g>>1
  f32x4 L[2][4];
#pragma unroll
  for (int s = 0; s < 4; ++s) {
    float bvv = fb[(2 * s + h) * 8 + j7];
    L[0][s] = (f32x4){bvv, bvv, bvv, bvv};
    L[1][s] = (f32x4){bvv, bvv, bvv, bvv};
  }
#pragma unroll
  for (int g = 0; g < 8; ++g) {
    int sg = g >> 1;
#pragma unroll
    for (int r = 0; r < 3; ++r) {
      f16x8 bf = bfv[(g * 3 + r) * 64 + lane];
#pragma unroll
      for (int i2 = 0; i2 < 2; ++i2) {
        f16x8 a = *(const f16x8*)&vtile[hpt[i2][r] + g * 8];
        L[i2][sg] = __builtin_amdgcn_mfma_f32_16x16x32_f16(a, bf, L[i2][sg], 0, 0, 0);
      }
    }
  }
#pragma unroll
  for (int i2 = 0; i2 < 2; ++i2)
#pragma unroll
    for (int s = 0; s < 4; ++s)
#pragma unroll
      for (int r = 0; r < 4; ++r) L[i2][s][r] = fmaxf(L[i2][s][r], 0.f);

  __syncthreads();  // vtile reads done; alias h1t
  f16* h1t = (f16*)smemf;  // [128][72], ch2 = n*8 + j1
#pragma unroll
  for (int i2 = 0; i2 < 2; ++i2)
#pragma unroll
    for (int s = 0; s < 4; ++s)
#pragma unroll
      for (int r = 0; r < 4; ++r)
        h1t[((2 * w + i2) * 16 + q * 4 + r) * 72 + (2 * s + h) * 8 + j7] =
            (f16)L[i2][s][r];
  __syncthreads();

  // CapsAct: K=64 over (j1, n) block-diag
  f32x4 H[2][4];
#pragma unroll
  for (int s = 0; s < 4; ++s) {
    float bvv = cab[(2 * s + h) * 8 + j7];
    H[0][s] = (f32x4){bvv, bvv, bvv, bvv};
    H[1][s] = (f32x4){bvv, bvv, bvv, bvv};
  }
#pragma unroll
  for (int c2 = 0; c2 < 2; ++c2) {
    f16x8 a2[2];
#pragma unroll
    for (int i2 = 0; i2 < 2; ++i2)
      a2[i2] = *(const f16x8*)&h1t[((2 * w + i2) * 16 + l15) * 72 + c2 * 32 + q * 8];
#pragma unroll
    for (int s = 0; s < 4; ++s) {
#pragma unroll
      for (int i2 = 0; i2 < 2; ++i2)
        H[i2][s] = __builtin_amdgcn_mfma_f32_16x16x32_f16(
            a2[i2], bcf[c2 * 4 + s], H[i2][s], 0, 0, 0);
    }
  }

  __syncthreads();  // h1t reads done; alias outbuf
  float* outbuf = smemf;  // [128][68], ch = j2*8 + n
#pragma unroll
  for (int i2 = 0; i2 < 2; ++i2)
#pragma unroll
    for (int s = 0; s < 4; ++s)
#pragma unroll
      for (int r = 0; r < 4; ++r)
        outbuf[((2 * w + i2) * 16 + q * 4 + r) * 68 + j7 * 8 + 2 * s + h] =
            H[i2][s][r];
  __syncthreads();

  for (int idx = tid; idx < 2048; idx += 256) {
    int p = idx >> 4, q4 = idx & 15;
    float4 val = *(float4*)&outbuf[p * 68 + q4 * 4];
    int gy = ty * 16 + (p >> 3), gx = tx * 8 + (p & 7);
    *(float4*)(out + ((b * HH + gy) * WW + gx) * 64 + q4 * 4) = val;
  }
}

extern "C" void kernel_launch(void* const* d_in, const int* in_sizes, int n_in,
                              void* d_out, int out_size, void* d_ws, size_t ws_size,
                              hipStream_t stream) {
  const float* inputs = (const float*)d_in[0];
  const float* attw   = (const float*)d_in[1];
  const float* ctw    = (const float*)d_in[2];
  const float* ctb    = (const float*)d_in[3];
  const float* few    = (const float*)d_in[4];
  const float* fb     = (const float*)d_in[5];
  const float* caw    = (const float*)d_in[6];
  const float* cab    = (const float*)d_in[7];
  float* out = (float*)d_out;
  float* ws  = (float*)d_ws;
  f16* vt = (f16*)(ws + 64) + VT_H;

  prep_kernel<<<(PREP_N + 255) / 256, 256, 0, stream>>>(attw, ctw, ctb, few, caw, ws);
  caps_stage1<<<32 * 32, 256, 0, stream>>>(inputs, ws, ctb, vt);
  caps_stage2<<<32 * 32, 256, 0, stream>>>(vt, ws, fb, cab, out);
}

// Round 14
// 141.022 us; speedup vs baseline: 1.9889x; 1.0499x over previous
//
#include <hip/hip_runtime.h>

#define HH 64
#define WW 64

typedef _Float16 f16;
typedef f16 f16x8 __attribute__((ext_vector_type(8)));
typedef f16 f16x4 __attribute__((ext_vector_type(4)));
typedef float f32x4 __attribute__((ext_vector_type(4)));

typedef __attribute__((address_space(3))) void lds_void;
typedef __attribute__((address_space(1))) const void gbl_void;

// ws: ws[0..63] = fp32 logit bias; then f16 region (offsets in halves):
#define M1_H 0         // [c][r*4+s][lane][j] : 49152
#define BU_H 49152     // [c][r*4+s][lane][j] : 49152
#define BF_H 98304     // [g][r][lane][j]     : 12288
#define BC_H 110592    // [c2][s][lane][j]    : 4096
#define VT_H 114688    // [pixel][ch=n*8+slot]: 8388608  (slot: d=2*(slot&3)+(slot>>2))
#define PREP_N (64 + 114688)

__global__ __launch_bounds__(256) void prep_kernel(
    const float* __restrict__ attw, const float* __restrict__ ctw,
    const float* __restrict__ ctb, const float* __restrict__ few,
    const float* __restrict__ caw, float* __restrict__ ws) {
  int i = blockIdx.x * 256 + threadIdx.x;
  if (i >= PREP_N) return;
  f16* hb = (f16*)(ws + 64);
  if (i < 64) {
    int s = i >> 4, l15 = i & 15;
    int o = 2 * s + (l15 >> 3), n = l15 & 7;
    float acc = 0.f;
    for (int c = 0; c < 8; ++c)
      for (int d = 0; d < 8; ++d)
        acc += ctb[c * 64 + d * 8 + n] * attw[d * 512 + c * 64 + n * 8 + o];
    ws[i] = acc;
    return;
  }
  int z = i - 64;
  if (z < BU_H) {
    int j = z & 7, lane = (z >> 3) & 63, rest = z >> 9;
    int rs = rest % 12, c = rest / 12;
    int r = rs >> 2, s = rs & 3;
    int q = lane >> 4, l15 = lane & 15;
    int t = r * 4 + q;
    int o = 2 * s + (l15 >> 3), n = l15 & 7;
    float acc = 0.f;
    if (t < 9)
      for (int d = 0; d < 8; ++d)
        acc += ctw[(t * 8 + j) * 512 + c * 64 + d * 8 + n] *
               attw[d * 512 + c * 64 + n * 8 + o];
    hb[M1_H + z] = (f16)acc;
  } else if (z < BF_H) {
    int z2 = z - BU_H;
    int j = z2 & 7, lane = (z2 >> 3) & 63, rest = z2 >> 9;
    int rs = rest % 12, c = rest / 12;
    int r = rs >> 2, s = rs & 3;
    int q = lane >> 4, l15 = lane & 15;
    int t = r * 4 + q;
    int d = 2 * s + (l15 >> 3), n = l15 & 7;
    float v = (t < 9) ? ctw[(t * 8 + j) * 512 + c * 64 + d * 8 + n] : 0.f;
    hb[z] = (f16)v;
  } else if (z < BC_H) {
    int z2 = z - BF_H;
    int j = z2 & 7, lane = (z2 >> 3) & 63, rest = z2 >> 9;
    int r = rest % 3, g = rest / 3;
    int q = lane >> 4, l15 = lane & 15;
    int t = r * 4 + q;
    int d = 2 * (j & 3) + (j >> 2);
    float v = 0.f;
    if (t < 9 && ((l15 >> 3) == (g & 1)))
      v = few[(t * 8 + d) * 64 + g * 8 + (l15 & 7)];
    hb[z] = (f16)v;
  } else if (z < VT_H) {
    int z2 = z - BC_H;
    int j = z2 & 7, lane = (z2 >> 3) & 63, rest = z2 >> 9;
    int s = rest & 3, c2 = rest >> 2;
    int q = lane >> 4, l15 = lane & 15;
    int nk = c2 * 4 + q;
    int nc = 2 * s + (l15 >> 3);
    float v = (nk == nc) ? caw[j * 64 + nc * 8 + (l15 & 7)] : 0.f;
    hb[z] = (f16)v;
  }
}

// Stage 1 (R14): R5's PROVEN skeleton (12KB c-slice dbuf staging, 16
// barriers, unroll-1 loops — 45.5us, ~100 VGPR) with the attb LDS buffer
// deleted via the R10/R12-verified register fold. The pass-2 c-loop stays
// unroll-1 (R12's full-unroll spill avoided) via a ROTATING att4: element 0
// is consumed each cc-iteration (static index, rule #20 safe), then the
// vector rotates by one slot (static shufflevector -> v_alignbit).
// LDS = xt 26064 + bstage 24576 = 50640 B => 3 blocks/CU; demand ~115 < the
// 128-VGPR residency-class cap => no spill possible.
__global__ __launch_bounds__(256, 2) void caps_stage1(
    const float* __restrict__ in, const float* __restrict__ ws,
    const float* __restrict__ ctb, f16* __restrict__ vt) {
  __shared__ f16 xt[181 * 72];     // 26064 B, hp=180 = zero row; vtmp in epilogue
  __shared__ f16 bstage[2][6144];  // 2 x 12 KB B-fragment c-slices
  int bid = blockIdx.x;
  int b = bid >> 5, t5 = bid & 31;
  int ty = t5 >> 3, tx = t5 & 7;
  int tid = threadIdx.x;
  int w = __builtin_amdgcn_readfirstlane(tid >> 6);
  int lane = tid & 63;
  int q = lane >> 4, l15 = lane & 15;
  int h = l15 >> 3, n = l15 & 7;

  const f16* hb = (const f16*)(ws + 64);
  const f16* m1h = hb + M1_H;
  const f16* buh = hb + BU_H;
  const float* lb = ws;

  // cooperative stage of one 12KB c-slice: wave w handles rows 3w..3w+2.
  auto stage = [&](const f16* src, int c, int bufi) {
    const f16* gs = src + c * 6144 + (w * 3) * 512 + lane * 8;
#pragma unroll
    for (int j = 0; j < 3; ++j)
      __builtin_amdgcn_global_load_lds(
          (gbl_void*)(gs + j * 512),
          (lds_void*)&bstage[bufi][(w * 3 + j) * 512], 16, 0, 0);
  };

  // prologue: stage M1 c=0,1 under the halo fill
  stage(m1h, 0, 0);
  stage(m1h, 1, 1);

  // fill halo tile (fp32 -> f16, transpose to ch = c*8+dd)
#pragma unroll
  for (int k = 0; k < 6; ++k) {
    int i = tid + k * 256;
    if (i < 181 * 8) {
      int c = i & 7, hp = i >> 3;
      float xs[8] = {0.f, 0.f, 0.f, 0.f, 0.f, 0.f, 0.f, 0.f};
      if (hp < 180) {
        int hy = hp / 10, hx = hp - hy * 10;
        int gy = ty * 16 + hy - 1, gx = tx * 8 + hx - 1;
        if (gy >= 0 && gy < HH && gx >= 0 && gx < WW) {
          const float* src = in + (((b * HH + gy) * WW + gx) * 64 + c);
#pragma unroll
          for (int d = 0; d < 8; ++d) xs[d] = src[d * 8];
        }
      }
      f16x8 pk;
#pragma unroll
      for (int d = 0; d < 8; ++d) pk[d] = (f16)xs[d];
      *(f16x8*)&xt[hp * 72 + c * 8] = pk;
    }
  }

  int hpt[2][3];
#pragma unroll
  for (int i2 = 0; i2 < 2; ++i2) {
    int pyA = (2 * w + i2) * 2 + h;
    int pxA = l15 & 7;
#pragma unroll
    for (int r = 0; r < 3; ++r) {
      int t = r * 4 + q;
      int hp = 180;
      if (t < 9) {
        int ky = t / 3, kx = t - ky * 3;
        hp = (pyA + ky) * 10 + pxA + kx;
      }
      hpt[i2][r] = hp * 72;
    }
  }

  f32x4 L[2][4];
#pragma unroll
  for (int s = 0; s < 4; ++s) {
    float v0 = lb[s * 16 + l15];
    L[0][s] = (f32x4){v0, v0, v0, v0};
    L[1][s] = (f32x4){v0, v0, v0, v0};
  }
  __syncthreads();  // halo ready + bstage c=0,1 landed (vmcnt drained)

  auto ldsB = [&](int bufi, f16x8(&bm)[12]) {
#pragma unroll
    for (int rs = 0; rs < 12; ++rs)
      bm[rs] = *(const f16x8*)&bstage[bufi][rs * 512 + lane * 8];
  };

  // ---- pass 1: logits GEMM, LDS-staged B (R5 verbatim) ----
  auto p1step = [&](int c, int bufi) {
    f16x8 bm[12];
    ldsB(bufi, bm);
    f16x8 a[2][3];
#pragma unroll
    for (int i2 = 0; i2 < 2; ++i2)
#pragma unroll
      for (int r = 0; r < 3; ++r)
        a[i2][r] = *(const f16x8*)&xt[hpt[i2][r] + c * 8];
#pragma unroll
    for (int i2 = 0; i2 < 2; ++i2)
#pragma unroll
      for (int s = 0; s < 4; ++s)
#pragma unroll
        for (int r = 0; r < 3; ++r)
          L[i2][s] = __builtin_amdgcn_mfma_f32_16x16x32_f16(
              a[i2][r], bm[r * 4 + s], L[i2][s], 0, 0, 0);
  };

#pragma unroll 1
  for (int cc = 0; cc < 4; ++cc) {
    int c0 = 2 * cc;
    p1step(c0, 0);
    __syncthreads();  // all waves done with buf0; staged buf1 landed
    if (cc < 3) stage(m1h, c0 + 2, 0); else stage(buh, 0, 0);
    p1step(c0 + 1, 1);
    __syncthreads();  // all waves done with buf1; staged buf0 landed
    if (cc < 3) stage(m1h, c0 + 3, 1); else stage(buh, 1, 1);
  }

  // pass2 bias c=0,1: latency hides under softmax
  float cbA[4], cbB[4];
#pragma unroll
  for (int s = 0; s < 4; ++s) {
    cbA[s] = ctb[s * 16 + l15];
    cbB[s] = ctb[64 + s * 16 + l15];
  }

  // ---- softmax -> att4 registers (R10/R12-verified fold layout) ----
  // att4[i2][r][s] = softmax weight for o = 2s + h (own h), column n
  f16x4 att4[2][4];
#pragma unroll
  for (int i2 = 0; i2 < 2; ++i2) {
#pragma unroll
    for (int r = 0; r < 4; ++r) {
      float v0 = L[i2][0][r], v1 = L[i2][1][r], v2 = L[i2][2][r], v3 = L[i2][3][r];
      float pm = fmaxf(fmaxf(v0, v1), fmaxf(v2, v3));
      float m = fmaxf(pm, __shfl_xor(pm, 8));
      float e0 = __expf(v0 - m), e1 = __expf(v1 - m);
      float e2 = __expf(v2 - m), e3 = __expf(v3 - m);
      float ps = e0 + e1 + e2 + e3;
      float inv = 1.f / (ps + __shfl_xor(ps, 8));
      f16x4 pk;
      pk[0] = (f16)(e0 * inv);
      pk[1] = (f16)(e1 * inv);
      pk[2] = (f16)(e2 * inv);
      pk[3] = (f16)(e3 * inv);
      att4[i2][r] = pk;
    }
  }
  __syncthreads();  // BU c=0,1 staging landed (staged at cc==3 above)

  // ---- pass 2: u GEMM + rotating register fold, unroll-1 (R5 skeleton) ----
  f32x4 V[2][4];
#pragma unroll
  for (int s = 0; s < 4; ++s) {
    V[0][s] = (f32x4){0.f, 0.f, 0.f, 0.f};
    V[1][s] = (f32x4){0.f, 0.f, 0.f, 0.f};
  }

  // par = c&1 (static at call sites); att slot for c is att4[..][0] after
  // (c>>1) rotations. Holder lane l15 = (c&1)*8 + n -> own if par==h.
  auto p2step = [&](int bufi, const float(&cb)[4], int par) {
    f16x8 bm[12];
    ldsB(bufi, bm);
#pragma unroll
    for (int i2 = 0; i2 < 2; ++i2) {
      f16x8 a[3];
#pragma unroll
      for (int r = 0; r < 3; ++r)
        a[r] = *(const f16x8*)&xt[hpt[i2][r] + (bufi ? 8 : 0)];  // placeholder
#pragma unroll
      for (int s = 0; s < 4; ++s) (void)a[0];
    }
  };
  (void)p2step;  // (unused placeholder removed below — real loop inline)

#pragma unroll 1
  for (int cc = 0; cc < 4; ++cc) {
    int c0 = 2 * cc;
    // ---- c = c0 (even, par = 0), buffer 0 ----
    {
      f16x8 bm[12];
      ldsB(0, bm);
#pragma unroll
      for (int i2 = 0; i2 < 2; ++i2) {
        f16x8 a[3];
#pragma unroll
        for (int r = 0; r < 3; ++r)
          a[r] = *(const f16x8*)&xt[hpt[i2][r] + c0 * 8];
        f32x4 U[4];
#pragma unroll
        for (int s = 0; s < 4; ++s) U[s] = (f32x4){cbA[s], cbA[s], cbA[s], cbA[s]};
#pragma unroll
        for (int s = 0; s < 4; ++s)
#pragma unroll
          for (int r = 0; r < 3; ++r)
            U[s] = __builtin_amdgcn_mfma_f32_16x16x32_f16(
                a[r], bm[r * 4 + s], U[s], 0, 0, 0);
#pragma unroll
        for (int r4 = 0; r4 < 4; ++r4) {
          float own = (float)att4[i2][r4][0];  // slot c0>>1 after rotations
          float par8 = __shfl_xor(own, 8);
          float af = (h == 0) ? own : par8;
#pragma unroll
          for (int s = 0; s < 4; ++s) V[i2][s][r4] += U[s][r4] * af;
        }
      }
    }
    __syncthreads();
    if (cc < 3) {
      stage(buh, c0 + 2, 0);
#pragma unroll
      for (int s = 0; s < 4; ++s) cbA[s] = ctb[(c0 + 2) * 64 + s * 16 + l15];
    }
    // ---- c = c0+1 (odd, par = 1), buffer 1 ----
    {
      f16x8 bm[12];
      ldsB(1, bm);
#pragma unroll
      for (int i2 = 0; i2 < 2; ++i2) {
        f16x8 a[3];
#pragma unroll
        for (int r = 0; r < 3; ++r)
          a[r] = *(const f16x8*)&xt[hpt[i2][r] + (c0 + 1) * 8];
        f32x4 U[4];
#pragma unroll
        for (int s = 0; s < 4; ++s) U[s] = (f32x4){cbB[s], cbB[s], cbB[s], cbB[s]};
#pragma unroll
        for (int s = 0; s < 4; ++s)
#pragma unroll
          for (int r = 0; r < 3; ++r)
            U[s] = __builtin_amdgcn_mfma_f32_16x16x32_f16(
                a[r], bm[r * 4 + s], U[s], 0, 0, 0);
#pragma unroll
        for (int r4 = 0; r4 < 4; ++r4) {
          float own = (float)att4[i2][r4][0];
          float par8 = __shfl_xor(own, 8);
          float af = (h == 1) ? own : par8;
#pragma unroll
          for (int s = 0; s < 4; ++s) V[i2][s][r4] += U[s][r4] * af;
        }
      }
    }
    __syncthreads();
    if (cc < 3) {
      stage(buh, c0 + 3, 1);
#pragma unroll
      for (int s = 0; s < 4; ++s) cbB[s] = ctb[(c0 + 3) * 64 + s * 16 + l15];
    }
    // rotate att4 one slot down (element 0 next iteration = slot cc+1)
#pragma unroll
    for (int i2 = 0; i2 < 2; ++i2)
#pragma unroll
      for (int r4 = 0; r4 < 4; ++r4)
        att4[i2][r4] =
            __builtin_shufflevector(att4[i2][r4], att4[i2][r4], 1, 2, 3, 0);
  }
  // loop ended with __syncthreads: all xt reads complete -> safe to alias

  // ---- epilogue: transpose V through vtmp (aliases xt), coalesced stores ----
  f16* vtmp = xt;
#pragma unroll
  for (int i2 = 0; i2 < 2; ++i2)
#pragma unroll
    for (int r = 0; r < 4; ++r) {
      int p = (2 * w + i2) * 16 + q * 4 + r;
      f16x4 st;
#pragma unroll
      for (int s = 0; s < 4; ++s) st[s] = (f16)V[i2][s][r];  // slot=h*4+s, d=2s+h
      *(f16x4*)&vtmp[p * 72 + n * 8 + h * 4] = st;
    }
  __syncthreads();
  for (int idx = tid; idx < 1024; idx += 256) {
    int p = idx >> 3, q2 = idx & 7;
    float4 val = *(float4*)&vtmp[p * 72 + q2 * 8];
    int gy = ty * 16 + (p >> 3), gx = tx * 8 + (p & 7);
    ((float4*)(vt + ((b * HH + gy) * WW + gx) * 64))[q2] = val;
  }
}

// Stage 2: R5-proven form verbatim (R1 structure + bcf preload under fill).
__global__ __launch_bounds__(256, 2) void caps_stage2(
    const f16* __restrict__ vt, const float* __restrict__ ws,
    const float* __restrict__ fb, const float* __restrict__ cab,
    float* __restrict__ out) {
  __shared__ float smemf[8704];  // 34.8 KB: vtile / h1t / outbuf aliased
  f16* vtile = (f16*)smemf;
  int bid = blockIdx.x;
  int b = bid >> 5, t5 = bid & 31;
  int ty = t5 >> 3, tx = t5 & 7;
  int tid = threadIdx.x;
  int w = __builtin_amdgcn_readfirstlane(tid >> 6);
  int lane = tid & 63;

  const f16x8* bfv = (const f16x8*)((const f16*)(ws + 64) + BF_H);
  const f16x8* bcv = (const f16x8*)((const f16*)(ws + 64) + BC_H);

  // preload CapsAct B-frags: latency hides under fill + FeaExt
  f16x8 bcf[8];
#pragma unroll
  for (int k = 0; k < 8; ++k) bcf[k] = bcv[k * 64 + lane];

  for (int i = tid; i < 181 * 8; i += 256) {
    int q2 = i & 7, hp = i >> 3;
    float4 val = make_float4(0.f, 0.f, 0.f, 0.f);
    if (hp < 180) {
      int hy = hp / 10, hx = hp - hy * 10;
      int gy = ty * 16 + hy - 1, gx = tx * 8 + hx - 1;
      if (gy >= 0 && gy < HH && gx >= 0 && gx < WW)
        val = ((const float4*)(vt + ((b * HH + gy) * WW + gx) * 64))[q2];
    }
    *(float4*)&vtile[hp * 72 + q2 * 8] = val;
  }
  __syncthreads();

  int q = lane >> 4, l15 = lane & 15;
  int h = l15 >> 3, j7 = l15 & 7;

  int hpt[2][3];
#pragma unroll
  for (int i2 = 0; i2 < 2; ++i2) {
    int pyA = (2 * w + i2) * 2 + h;
#pragma unroll
    for (int r = 0; r < 3; ++r) {
      int t = r * 4 + q;
      int hp = 180;
      if (t < 9) {
        int ky = t / 3, kx = t - ky * 3;
        hp = (pyA + ky) * 10 + j7 + kx;
      }
      hpt[i2][r] = hp * 72;
    }
  }

  // FeaExt: col (n=2s+h, j=j7); input chunk g feeds only s = g>>1
  f32x4 L[2][4];
#pragma unroll
  for (int s = 0; s < 4; ++s) {
    float bvv = fb[(2 * s + h) * 8 + j7];
    L[0][s] = (f32x4){bvv, bvv, bvv, bvv};
    L[1][s] = (f32x4){bvv, bvv, bvv, bvv};
  }
#pragma unroll
  for (int g = 0; g < 8; ++g) {
    int sg = g >> 1;
#pragma unroll
    for (int r = 0; r < 3; ++r) {
      f16x8 bf = bfv[(g * 3 + r) * 64 + lane];
#pragma unroll
      for (int i2 = 0; i2 < 2; ++i2) {
        f16x8 a = *(const f16x8*)&vtile[hpt[i2][r] + g * 8];
        L[i2][sg] = __builtin_amdgcn_mfma_f32_16x16x32_f16(a, bf, L[i2][sg], 0, 0, 0);
      }
    }
  }
#pragma unroll
  for (int i2 = 0; i2 < 2; ++i2)
#pragma unroll
    for (int s = 0; s < 4; ++s)
#pragma unroll
      for (int r = 0; r < 4; ++r) L[i2][s][r] = fmaxf(L[i2][s][r], 0.f);

  __syncthreads();  // vtile reads done; alias h1t
  f16* h1t = (f16*)smemf;  // [128][72], ch2 = n*8 + j1
#pragma unroll
  for (int i2 = 0; i2 < 2; ++i2)
#pragma unroll
    for (int s = 0; s < 4; ++s)
#pragma unroll
      for (int r = 0; r < 4; ++r)
        h1t[((2 * w + i2) * 16 + q * 4 + r) * 72 + (2 * s + h) * 8 + j7] =
            (f16)L[i2][s][r];
  __syncthreads();

  // CapsAct: K=64 over (j1, n) block-diag
  f32x4 H[2][4];
#pragma unroll
  for (int s = 0; s < 4; ++s) {
    float bvv = cab[(2 * s + h) * 8 + j7];
    H[0][s] = (f32x4){bvv, bvv, bvv, bvv};
    H[1][s] = (f32x4){bvv, bvv, bvv, bvv};
  }
#pragma unroll
  for (int c2 = 0; c2 < 2; ++c2) {
    f16x8 a2[2];
#pragma unroll
    for (int i2 = 0; i2 < 2; ++i2)
      a2[i2] = *(const f16x8*)&h1t[((2 * w + i2) * 16 + l15) * 72 + c2 * 32 + q * 8];
#pragma unroll
    for (int s = 0; s < 4; ++s) {
#pragma unroll
      for (int i2 = 0; i2 < 2; ++i2)
        H[i2][s] = __builtin_amdgcn_mfma_f32_16x16x32_f16(
            a2[i2], bcf[c2 * 4 + s], H[i2][s], 0, 0, 0);
    }
  }

  __syncthreads();  // h1t reads done; alias outbuf
  float* outbuf = smemf;  // [128][68], ch = j2*8 + n
#pragma unroll
  for (int i2 = 0; i2 < 2; ++i2)
#pragma unroll
    for (int s = 0; s < 4; ++s)
#pragma unroll
      for (int r = 0; r < 4; ++r)
        outbuf[((2 * w + i2) * 16 + q * 4 + r) * 68 + j7 * 8 + 2 * s + h] =
            H[i2][s][r];
  __syncthreads();

  for (int idx = tid; idx < 2048; idx += 256) {
    int p = idx >> 4, q4 = idx & 15;
    float4 val = *(float4*)&outbuf[p * 68 + q4 * 4];
    int gy = ty * 16 + (p >> 3), gx = tx * 8 + (p & 7);
    *(float4*)(out + ((b * HH + gy) * WW + gx) * 64 + q4 * 4) = val;
  }
}

extern "C" void kernel_launch(void* const* d_in, const int* in_sizes, int n_in,
                              void* d_out, int out_size, void* d_ws, size_t ws_size,
                              hipStream_t stream) {
  const float* inputs = (const float*)d_in[0];
  const float* attw   = (const float*)d_in[1];
  const float* ctw    = (const float*)d_in[2];
  const float* ctb    = (const float*)d_in[3];
  const float* few    = (const float*)d_in[4];
  const float* fb     = (const float*)d_in[5];
  const float* caw    = (const float*)d_in[6];
  const float* cab    = (const float*)d_in[7];
  float* out = (float*)d_out;
  float* ws  = (float*)d_ws;
  f16* vt = (f16*)(ws + 64) + VT_H;

  prep_kernel<<<(PREP_N + 255) / 256, 256, 0, stream>>>(attw, ctw, ctb, few, caw, ws);
  caps_stage1<<<32 * 32, 256, 0, stream>>>(inputs, ws, ctb, vt);
  caps_stage2<<<32 * 32, 256, 0, stream>>>(vt, ws, fb, cab, out);
}